// Round 1
// baseline (47.346 us; speedup 1.0000x reference)
//
#include <hip/hip_runtime.h>

// 3x3 VALID correlation on 4096x4096 fp32, output 4094x4094 fp32, + bias.
// out[r][c] = sum_{kh,kw} X[r+kh][c+kw] * W[kh][kw] + bias
// (jax.lax.conv_general_dilated does NOT flip the kernel.)

constexpr int Hin = 4096;
constexpr int Win = 4096;
constexpr int OH  = 4094;
constexpr int OW  = 4094;

__global__ __launch_bounds__(256) void conv3x3_kernel(
    const float* __restrict__ X, const float* __restrict__ Wt,
    const float* __restrict__ B, float* __restrict__ Out)
{
    int t  = blockIdx.x * 256 + threadIdx.x;
    int r  = t >> 10;           // 1024 threads per output row (covers 4096 cols)
    int c0 = (t & 1023) << 2;   // 4 outputs per thread
    if (r >= OH) return;

    float wgt[9];
#pragma unroll
    for (int i = 0; i < 9; ++i) wgt[i] = Wt[i];
    const float bias = B[0];

    float acc0 = bias, acc1 = bias, acc2 = bias, acc3 = bias;

#pragma unroll
    for (int kh = 0; kh < 3; ++kh) {
        const float* row = X + (size_t)(r + kh) * Win + c0;
        // c0 <= 4092, so [c0..c0+3] is always in-bounds; guard the 2 extras.
        float4 a = *reinterpret_cast<const float4*>(row);
        float v4 = ((c0 + 4) < Win) ? row[4] : 0.f;
        float v5 = ((c0 + 5) < Win) ? row[5] : 0.f;
        float v[6] = {a.x, a.y, a.z, a.w, v4, v5};
#pragma unroll
        for (int kw = 0; kw < 3; ++kw) {
            float wv = wgt[kh * 3 + kw];
            acc0 = fmaf(v[kw + 0], wv, acc0);
            acc1 = fmaf(v[kw + 1], wv, acc1);
            acc2 = fmaf(v[kw + 2], wv, acc2);
            acc3 = fmaf(v[kw + 3], wv, acc3);
        }
    }

    size_t o = (size_t)r * OW + c0;
    if (c0 + 3 < OW) {
        // 8-byte aligned: r*OW is even, c0 is a multiple of 4.
        *reinterpret_cast<float2*>(Out + o)     = make_float2(acc0, acc1);
        *reinterpret_cast<float2*>(Out + o + 2) = make_float2(acc2, acc3);
    } else {
        if (c0 + 0 < OW) Out[o + 0] = acc0;
        if (c0 + 1 < OW) Out[o + 1] = acc1;
        if (c0 + 2 < OW) Out[o + 2] = acc2;
        if (c0 + 3 < OW) Out[o + 3] = acc3;
    }
}

extern "C" void kernel_launch(void* const* d_in, const int* in_sizes, int n_in,
                              void* d_out, int out_size, void* d_ws, size_t ws_size,
                              hipStream_t stream) {
    const float* X  = (const float*)d_in[0];
    const float* Wt = (const float*)d_in[1];
    const float* B  = (const float*)d_in[2];
    float* Out      = (float*)d_out;

    // 1024 threads per row * 4094 rows, 256 threads/block
    int total_threads = 1024 * OH;
    int blocks = (total_threads + 255) / 256;   // 16376
    conv3x3_kernel<<<blocks, 256, 0, stream>>>(X, Wt, B, Out);
}